// Round 10
// baseline (253.833 us; speedup 1.0000x reference)
//
#include <hip/hip_runtime.h>

// FFB encoder fused kernel, MI355X (gfx950). Round 20.
//  R19 post-mortem: sinG reg-carry spilled catastrophically (WRITE 228MB) --
//  5th spill at a register boundary. Law: any cross-barrier live state on top
//  of C1=64-AGPR spills. The 64x64-per-wave tile IS the structural problem.
//  R20: 512-thread blocks, 8 waves, wave (wr,wc) owns a 32x64 GEMM1 tile:
//   - C1 = 32 AGPR (halved). Epilogue 64 trans/wave (halved). 1 A-frag/kb.
//   - __launch_bounds__(512,4): 2 blocks/CU = 4 waves/SIMD, cap 128 unified;
//     worst-phase live ~114 -> spill-free occupancy gain (what R13-R16 chased).
//   - head back to R11's proven 16x16x32 (whh 16-col pack): 16 tiles / 8
//     waves = 2 each, B-frags shared across the wave's two row-tiles.
//   - LDS unchanged 39936 B/block; 2 blocks = 80KB/CU.
//  Math identical to R18 (head k-grouping = R11's, passed 0.0625).
//  Tripwires: WRITE 32.77MB / FETCH ~14.5MB, VGPR <= 128. If spill or
//  dur >= 152: revert to R18, structural ceiling.
//  Kept: operand-swapped GEMM1/grid, packed-b64 stores, raw v_sin (no fract),
//  K5-prescaled weights/biases, bias-at-use epilogue, stride-264 LDS,
//  2 barriers/layer, ring-4/dist-3 GEMM1 B-stream.

#define TM 64
#define XSTRIDE 264
#define GSTRIDE 48
#define K5 0.79577471545947667f         // 5/(2*pi)

typedef __attribute__((ext_vector_type(8))) _Float16 v8h;
typedef __attribute__((ext_vector_type(4))) _Float16 v4h;
typedef __attribute__((ext_vector_type(4))) float v4f;
typedef __attribute__((ext_vector_type(16))) float v16f;

#define MFMA32H(a, b, c) __builtin_amdgcn_mfma_f32_32x32x16_f16(a, b, c, 0, 0, 0)
#define MFMA16H(a, b, c) __builtin_amdgcn_mfma_f32_16x16x32_f16(a, b, c, 0, 0, 0)

// Raw v_sin_f32: input in revolutions; HW range reduction covers |u| << 256.
__device__ __forceinline__ float sin_hw(float u) {
    return __builtin_amdgcn_sinf(u);
}

__device__ __forceinline__ short f16s(float x) {      // RNE f32->f16
    _Float16 hh = (_Float16)x;
    return __builtin_bit_cast(short, hh);
}

// ---------------- weight packing ----------------
// wh   f16: [l][kb16][nt8][lane64][8]  (327680 shorts), scaled by K5
// whh  f16: [l][kb8][nt4][lane64][8]   (81920 shorts),  scaled by K5  (16-col tiles, R11 format)
// gf   f16: [l][nt8][lane64][8]        (20480 shorts),  ffnA*2^(l-1)
// bhs  f32: [l][256]  = bh*K5          (1280 floats)
// bhhs f32: [l][64]   = bhh*K5         (320 floats)
__global__ __launch_bounds__(256) void ffb_pack(
    const float* __restrict__ Wh, const float* __restrict__ Whh,
    const float* __restrict__ ffnA,
    const float* __restrict__ bh, const float* __restrict__ bhh,
    short* __restrict__ wh, short* __restrict__ whh, short* __restrict__ gf,
    float* __restrict__ bhs, float* __restrict__ bhhs)
{
    int t = blockIdx.x * 256 + threadIdx.x;
    if (t < 40960) {                       // (l, kb, nt, lane)
        int lane = t & 63, nt = (t >> 6) & 7, kb = (t >> 9) & 15, l = t >> 13;
        int n = nt * 32 + (lane & 31);
        int k0 = kb * 16 + (lane >> 5) * 8;
        short hs[8];
        #pragma unroll
        for (int jj = 0; jj < 8; jj++)
            hs[jj] = f16s(Wh[(l * 256 + k0 + jj) * 256 + n] * K5);
        *(v8h*)(wh + t * 8) = *(v8h*)hs;
    } else if (t < 51200) {
        int t2 = t - 40960;                // (l, kb8, nt4, lane)  R11 format
        int lane = t2 & 63, nt = (t2 >> 6) & 3, kb = (t2 >> 8) & 7, l = t2 >> 11;
        int n = nt * 16 + (lane & 15);
        int k0 = kb * 32 + (lane >> 4) * 8;
        short hs[8];
        #pragma unroll
        for (int jj = 0; jj < 8; jj++)
            hs[jj] = f16s(Whh[(l * 256 + k0 + jj) * 64 + n] * K5);
        *(v8h*)(whh + t2 * 8) = *(v8h*)hs;
    } else if (t < 53760) {
        int t3 = t - 51200;                // (l, nt, lane)
        int lane = t3 & 63, nt = (t3 >> 6) & 7, l = t3 >> 9;
        int n = nt * 32 + (lane & 31);
        const float sc = 0.5f * (float)(1 << l);       // 2^(l-1), exact
        short hs[8];
        #pragma unroll
        for (int jj = 0; jj < 8; jj++)
            hs[jj] = f16s(ffnA[(l * 8 + jj) * 256 + n] * sc);
        *(v8h*)(gf + t3 * 8) = *(v8h*)hs;
    } else if (t < 55040) {
        int t4 = t - 53760;
        bhs[t4] = bh[t4] * K5;
    } else if (t < 55360) {
        int t5 = t - 55040;
        bhhs[t5] = bhh[t5] * K5;
    }
}

// ---------------- main fused kernel: 512 threads, 8 waves ----------------
__global__ __launch_bounds__(512, 4) void ffb_main(
    const float* __restrict__ pos, const float* __restrict__ gfeat,
    const float* __restrict__ W0, const float* __restrict__ b0,
    const float* __restrict__ bhs, const float* __restrict__ bhhs,
    const short* __restrict__ wh, const short* __restrict__ whh,
    const short* __restrict__ gf,
    float* __restrict__ out)
{
    __shared__ __align__(16) short s_x[TM * XSTRIDE];   // f16  (33792 B)
    __shared__ __align__(16) short s_g[TM * GSTRIDE];   // f16  (6144 B)

    const int tid = threadIdx.x;
    const int row0 = blockIdx.x * TM;
    const int lane = tid & 63;
    const int w = tid >> 6;                // 0..7
    const int m32 = lane & 31;
    const int h = lane >> 5;
    const int i16 = lane & 15;
    const int q = lane >> 4;
    const int wr = w >> 2;                 // GEMM1 row-half (0/1); head row-pair
    const int wc = w & 3;                  // GEMM1 col-quarter; head col-16-tile

    for (int k2 = tid; k2 < TM * 40; k2 += 512) {
        int r = k2 / 40, f = k2 % 40;
        s_g[r * GSTRIDE + f] = f16s(gfeat[row0 * 40 + k2]);
    }

    // layer 0: x = sin(5*(pos@W0 + b0)); wave w = rows w*8..+7,
    // thread = cols 4*lane..+3; f32 math; packed b64 stores.
    {
        const int c0 = 4 * lane;
        const int r0 = w * 8;
        float w0c[3][4], bq[4];
        #pragma unroll
        for (int j = 0; j < 4; j++) {
            w0c[0][j] = W0[c0 + j];
            w0c[1][j] = W0[256 + c0 + j];
            w0c[2][j] = W0[512 + c0 + j];
            bq[j] = b0[c0 + j];
        }
        #pragma unroll 4
        for (int r = 0; r < 8; r++) {
            const float p0 = pos[(row0 + r0 + r) * 3 + 0];   // wave-uniform
            const float p1 = pos[(row0 + r0 + r) * 3 + 1];
            const float p2 = pos[(row0 + r0 + r) * 3 + 2];
            v4h pv;
            #pragma unroll
            for (int j = 0; j < 4; j++) {
                float d = p0 * w0c[0][j] + p1 * w0c[1][j] + p2 * w0c[2][j] + bq[j];
                pv[j] = (_Float16)sin_hw(d * K5);
            }
            *(v4h*)(s_x + (r0 + r) * XSTRIDE + c0) = pv;
        }
    }
    __syncthreads();

    float cout[2][4];
    #pragma unroll
    for (int ii = 0; ii < 2; ii++)
        #pragma unroll
        for (int r = 0; r < 4; r++) cout[ii][r] = 0.f;

    // GEMM1 x-frag base: rows wr*32 + m32, + kb*16 along k
    const int a1off = (wr * 32 + m32) * XSTRIDE + h * 8;

    for (int l = 0; l < 5; l++) {
        // ---- C1 ZERO-init (bias added in epilogue; 32 AGPR total) ----
        v16f C1[2];
        #pragma unroll
        for (int r = 0; r < 16; r++) { C1[0][r] = 0.f; C1[1][r] = 0.f; }

        // ---- GEMM1 (swapped): wh = A, x = B; wave tile 32 rows x 64 cols;
        //      ring-4/dist-3 B-stream (nt pair 2*wc, 2*wc+1) ----
        {
            const short* bp = wh + l * 65536 + (2 * wc) * 512 + lane * 8;
            v8h rb0[4], rb1[4];
            #pragma unroll
            for (int p = 0; p < 3; p++) {
                rb0[p] = *(const v8h*)(bp + p * 4096);
                rb1[p] = *(const v8h*)(bp + p * 4096 + 512);
            }
            #pragma unroll
            for (int kb = 0; kb < 16; kb++) {
                if (kb + 3 < 16) {
                    rb0[(kb + 3) & 3] = *(const v8h*)(bp + (kb + 3) * 4096);
                    rb1[(kb + 3) & 3] = *(const v8h*)(bp + (kb + 3) * 4096 + 512);
                }
                v8h a = *(const v8h*)&s_x[a1off + kb * 16];
                C1[0] = MFMA32H(rb0[kb & 3], a, C1[0]);
                C1[1] = MFMA32H(rb1[kb & 3], a, C1[1]);
            }
        }
        __syncthreads();   // all waves done reading x_l

        // ---- epilogue: x = sin(C1 + bias) + sin(G); G-MFMAs hoisted;
        //      bias v4f at use; packed b64 stores ----
        {
            v8h gb0 = *(const v8h*)(gf + ((l * 8 + wc * 2 + 0) * 64 + lane) * 8);
            v8h gb1 = *(const v8h*)(gf + ((l * 8 + wc * 2 + 1) * 64 + lane) * 8);
            v8h ga = *(const v8h*)&s_g[(wr * 32 + m32) * GSTRIDE + l * 8];
            v16f Z = {};
            v16f G0 = MFMA32H(gb0, ga, Z);
            v16f G1 = MFMA32H(gb1, ga, Z);
            const float* bl = bhs + l * 256 + wc * 64 + h * 4;
            const int rowb = (wr * 32 + m32) * XSTRIDE;
            #pragma unroll
            for (int tt = 0; tt < 2; tt++) {
                const int cb = rowb + wc * 64 + tt * 32 + h * 4;
                #pragma unroll
                for (int rq = 0; rq < 4; rq++) {
                    v4f b = *(const v4f*)(bl + tt * 32 + rq * 8);
                    v4h pv;
                    #pragma unroll
                    for (int j = 0; j < 4; j++) {
                        float gv = tt ? G1[rq * 4 + j] : G0[rq * 4 + j];
                        pv[j] = (_Float16)(sin_hw(C1[tt][rq * 4 + j] + b[j])
                                         + sin_hw(gv));
                    }
                    *(v4h*)(s_x + cb + rq * 8) = pv;    // 8B aligned
                }
            }
        }
        __syncthreads();   // new x visible

        // ---- head GEMM, 16x16x32 (R11 path): wave = col-tile wc (16 cols),
        //      row-tiles m = wr*2 + {0,1}; B-frags shared across both ----
        {
            const float b2 = bhhs[l * 64 + wc * 16 + i16];
            v4f C2[2];
            #pragma unroll
            for (int ii = 0; ii < 2; ii++) C2[ii] = (v4f){b2, b2, b2, b2};
            const short* bp2 = whh + l * 16384 + wc * 512 + lane * 8;
            v8h bc[8];
            #pragma unroll
            for (int kb = 0; kb < 8; kb++)
                bc[kb] = *(const v8h*)(bp2 + kb * 2048);
            #pragma unroll
            for (int kb = 0; kb < 8; kb++) {
                #pragma unroll
                for (int ii = 0; ii < 2; ii++) {
                    const int m = wr * 2 + ii;
                    v8h a = *(const v8h*)&s_x[(m * 16 + i16) * XSTRIDE + q * 8 + kb * 32];
                    C2[ii] = MFMA16H(a, bc[kb], C2[ii]);
                }
            }
            #pragma unroll
            for (int ii = 0; ii < 2; ii++)
                #pragma unroll
                for (int r = 0; r < 4; r++)
                    cout[ii][r] += sin_hw(C2[ii][r]);
        }
        // no barrier: next GEMM1 reads same x; overwrites after its own barrier
    }

    // ---- store x_out: row = (wr*2+ii)*16 + q*4 + r, col = wc*16 + i16 ----
    #pragma unroll
    for (int ii = 0; ii < 2; ii++)
        #pragma unroll
        for (int r = 0; r < 4; r++)
            out[(row0 + (wr * 2 + ii) * 16 + q * 4 + r) * 64 + wc * 16 + i16]
                = cout[ii][r];
}

extern "C" void kernel_launch(void* const* d_in, const int* in_sizes, int n_in,
                              void* d_out, int out_size, void* d_ws, size_t ws_size,
                              hipStream_t stream) {
    const float* pos   = (const float*)d_in[0];
    const float* gfeat = (const float*)d_in[1];
    const float* ffnA  = (const float*)d_in[2];
    const float* W0    = (const float*)d_in[3];
    const float* b0    = (const float*)d_in[4];
    const float* Wh    = (const float*)d_in[5];
    const float* bh    = (const float*)d_in[6];
    const float* Whh   = (const float*)d_in[7];
    const float* bhh   = (const float*)d_in[8];
    float* out = (float*)d_out;
    const int N = in_sizes[0] / 3;

    // ws: wh 327680 | whh 81920 | gf 20480 shorts, then bhs 1280 | bhhs 320 f32
    short* wh  = (short*)d_ws;
    short* whh = wh + 327680;
    short* gf  = whh + 81920;
    float* bhs  = (float*)(gf + 20480);     // byte offset 860160, 16B aligned
    float* bhhs = bhs + 1280;

    ffb_pack<<<217, 256, 0, stream>>>(Wh, Whh, ffnA, bh, bhh,
                                      wh, whh, gf, bhs, bhhs);
    ffb_main<<<N / TM, 512, 0, stream>>>(pos, gfeat, W0, b0, bhs, bhhs,
                                         wh, whh, gf, out);
}

// Round 11
// 238.868 us; speedup vs baseline: 1.0626x; 1.0626x over previous
//
#include <hip/hip_runtime.h>

// FFB encoder fused kernel, MI355X (gfx950). Round 21.
//  R20 post-mortem: smaller-state/8-wave variant WORSE (192us): conflicts 3x
//  (16x16 head), MfmaUtil 26.6, despite 42% occupancy, zero spill. Verdict:
//  occupancy is not the lever in EITHER direction (R13-16 squeeze spilled;
//  R20 shrink degraded). Counters now prove both pipes' busy-cycles == the
//  arithmetic work (MfmaUtil 33.7 == 109K MFMA-issue cyc; VALUBusy 40 == ~750
//  VALU cyc/wave-layer): the wall is ~60% dependency/BARRIER stall.
//  R21: the one untested axis -- barrier count. Double-buffer s_x:
//   - 2 barriers/layer -> 1 (WAR epilogue-write vs GEMM1-read eliminated by
//     writing the other buffer; only RAW head-read vs epilogue-write remains).
//   - barrier-free region per wave = {head(l), GEMM1(l+1), epilogue(l+1)}:
//     long MFMA+VALU mixed body -> wave skew overlaps pipes WITHIN a block.
//   - LDS 73728 B -> 2 blocks/CU (8 waves). launch_bounds(256,2) -> 256-reg
//     cap: spill-impossible; bias back into C1-init (R12-proven, -64 adds).
//   - per-wave code otherwise identical to R18 (154us best).
//  A/B: barrier theory -> ~130-145us; occupancy-dominates -> >=165.
//  Tripwires: WRITE 32.77MB / FETCH 14.5MB; absmax 0.0625. If dur >= 154:
//  revert R18, structural ceiling.
//  Kept: operand-swapped GEMM1/grid, ring-4/dist-3 both GEMMs, G-hoist,
//  raw v_sin (no fract), packed-b64 layer-0 & epilogue stores, 32x32x16 head,
//  K5-prescaled weights/biases, stride-264 LDS.

#define TM 64
#define XSTRIDE 264
#define GSTRIDE 48
#define K5 0.79577471545947667f         // 5/(2*pi)

typedef __attribute__((ext_vector_type(8))) _Float16 v8h;
typedef __attribute__((ext_vector_type(4))) _Float16 v4h;
typedef __attribute__((ext_vector_type(4))) float v4f;
typedef __attribute__((ext_vector_type(16))) float v16f;

#define MFMA32H(a, b, c) __builtin_amdgcn_mfma_f32_32x32x16_f16(a, b, c, 0, 0, 0)

// Raw v_sin_f32: input in revolutions; HW range reduction covers |u| << 256.
__device__ __forceinline__ float sin_hw(float u) {
    return __builtin_amdgcn_sinf(u);
}

__device__ __forceinline__ short f16s(float x) {      // RNE f32->f16
    _Float16 hh = (_Float16)x;
    return __builtin_bit_cast(short, hh);
}

// ---------------- weight packing ----------------
// wh   f16: [l][kb16][nt8][lane64][8]  (327680 shorts), scaled by K5
// whh  f16: [l][kb16][nt2][lane64][8]  (81920 shorts),  scaled by K5  (32-col tiles)
// gf   f16: [l][nt8][lane64][8]        (20480 shorts),  ffnA*2^(l-1)
// bhs  f32: [l][256]  = bh*K5          (1280 floats)
// bhhs f32: [l][64]   = bhh*K5         (320 floats)
__global__ __launch_bounds__(256) void ffb_pack(
    const float* __restrict__ Wh, const float* __restrict__ Whh,
    const float* __restrict__ ffnA,
    const float* __restrict__ bh, const float* __restrict__ bhh,
    short* __restrict__ wh, short* __restrict__ whh, short* __restrict__ gf,
    float* __restrict__ bhs, float* __restrict__ bhhs)
{
    int t = blockIdx.x * 256 + threadIdx.x;
    if (t < 40960) {                       // (l, kb, nt, lane)
        int lane = t & 63, nt = (t >> 6) & 7, kb = (t >> 9) & 15, l = t >> 13;
        int n = nt * 32 + (lane & 31);
        int k0 = kb * 16 + (lane >> 5) * 8;
        short hs[8];
        #pragma unroll
        for (int jj = 0; jj < 8; jj++)
            hs[jj] = f16s(Wh[(l * 256 + k0 + jj) * 256 + n] * K5);
        *(v8h*)(wh + t * 8) = *(v8h*)hs;
    } else if (t < 51200) {
        int t2 = t - 40960;                // (l, kb16, nt2, lane)
        int lane = t2 & 63, nt = (t2 >> 6) & 1, kb = (t2 >> 7) & 15, l = t2 >> 11;
        int n = nt * 32 + (lane & 31);
        int k0 = kb * 16 + (lane >> 5) * 8;
        short hs[8];
        #pragma unroll
        for (int jj = 0; jj < 8; jj++)
            hs[jj] = f16s(Whh[(l * 256 + k0 + jj) * 64 + n] * K5);
        *(v8h*)(whh + t2 * 8) = *(v8h*)hs;
    } else if (t < 53760) {
        int t3 = t - 51200;                // (l, nt, lane)
        int lane = t3 & 63, nt = (t3 >> 6) & 7, l = t3 >> 9;
        int n = nt * 32 + (lane & 31);
        const float sc = 0.5f * (float)(1 << l);       // 2^(l-1), exact
        short hs[8];
        #pragma unroll
        for (int jj = 0; jj < 8; jj++)
            hs[jj] = f16s(ffnA[(l * 8 + jj) * 256 + n] * sc);
        *(v8h*)(gf + t3 * 8) = *(v8h*)hs;
    } else if (t < 55040) {
        int t4 = t - 53760;
        bhs[t4] = bh[t4] * K5;
    } else if (t < 55360) {
        int t5 = t - 55040;
        bhhs[t5] = bhh[t5] * K5;
    }
}

// ---------------- main fused kernel ----------------
__global__ __launch_bounds__(256, 2) void ffb_main(
    const float* __restrict__ pos, const float* __restrict__ gfeat,
    const float* __restrict__ W0, const float* __restrict__ b0,
    const float* __restrict__ bhs, const float* __restrict__ bhhs,
    const short* __restrict__ wh, const short* __restrict__ whh,
    const short* __restrict__ gf,
    float* __restrict__ out)
{
    __shared__ __align__(16) short s_x[2][TM * XSTRIDE];  // f16 (67584 B, dbuf)
    __shared__ __align__(16) short s_g[TM * GSTRIDE];     // f16 (6144 B)

    const int tid = threadIdx.x;
    const int row0 = blockIdx.x * TM;
    const int lane = tid & 63;
    const int w = tid >> 6;
    const int m32 = lane & 31;
    const int h = lane >> 5;
    const int mq = w >> 1;                 // head-GEMM quadrant row-tile
    const int tq = w & 1;                  // head-GEMM quadrant col-tile

    for (int k2 = tid; k2 < TM * 40; k2 += 256) {
        int r = k2 / 40, f = k2 % 40;
        s_g[r * GSTRIDE + f] = f16s(gfeat[row0 * 40 + k2]);
    }

    // layer 0: x = sin(5*(pos@W0 + b0)) -> s_x[0]; wave w = rows w*16..+15,
    // thread = cols 4*lane..+3; f32 math; packed b64 stores.
    {
        const int c0 = 4 * lane;
        const int r0 = w * 16;
        float w0c[3][4], bq[4];
        #pragma unroll
        for (int j = 0; j < 4; j++) {
            w0c[0][j] = W0[c0 + j];
            w0c[1][j] = W0[256 + c0 + j];
            w0c[2][j] = W0[512 + c0 + j];
            bq[j] = b0[c0 + j];
        }
        #pragma unroll 4
        for (int r = 0; r < 16; r++) {
            const float p0 = pos[(row0 + r0 + r) * 3 + 0];   // wave-uniform
            const float p1 = pos[(row0 + r0 + r) * 3 + 1];
            const float p2 = pos[(row0 + r0 + r) * 3 + 2];
            v4h pv;
            #pragma unroll
            for (int j = 0; j < 4; j++) {
                float d = p0 * w0c[0][j] + p1 * w0c[1][j] + p2 * w0c[2][j] + bq[j];
                pv[j] = (_Float16)sin_hw(d * K5);
            }
            *(v4h*)(&s_x[0][(r0 + r) * XSTRIDE + c0]) = pv;
        }
    }
    __syncthreads();

    float cout[16];
    #pragma unroll
    for (int r = 0; r < 16; r++) cout[r] = 0.f;

    const int a1off0 = m32 * XSTRIDE + h * 8;            // x-row tile 0, + kb*16
    const int a1off1 = (32 + m32) * XSTRIDE + h * 8;     // x-row tile 1

    for (int l = 0; l < 5; l++) {
        const short* sxr = s_x[l & 1];         // x_l (read)
        short* sxw = s_x[(l + 1) & 1];         // x_{l+1} (write)

        // ---- C1 init with bias (K5-prescaled; R12-proven layout) ----
        // wcol(reg r, h) = w*64 + tt*32 + 8*(r>>2) + 4*h + (r&3)
        v16f C1[2][2];
        {
            const float* bl = bhs + l * 256 + w * 64 + h * 4;
            #pragma unroll
            for (int tt = 0; tt < 2; tt++)
                #pragma unroll
                for (int rq = 0; rq < 4; rq++) {
                    v4f b = *(const v4f*)(bl + tt * 32 + rq * 8);
                    #pragma unroll
                    for (int j = 0; j < 4; j++) {
                        C1[0][tt][rq * 4 + j] = b[j];
                        C1[1][tt][rq * 4 + j] = b[j];
                    }
                }
        }

        // ---- GEMM1 (swapped): wh = A, x = B; ring-4/dist-3; reads sxr ----
        {
            const short* bp = wh + l * 65536 + (2 * w) * 512 + lane * 8;
            v8h rb0[4], rb1[4];
            #pragma unroll
            for (int p = 0; p < 3; p++) {
                rb0[p] = *(const v8h*)(bp + p * 4096);
                rb1[p] = *(const v8h*)(bp + p * 4096 + 512);
            }
            #pragma unroll
            for (int kb = 0; kb < 16; kb++) {
                if (kb + 3 < 16) {
                    rb0[(kb + 3) & 3] = *(const v8h*)(bp + (kb + 3) * 4096);
                    rb1[(kb + 3) & 3] = *(const v8h*)(bp + (kb + 3) * 4096 + 512);
                }
                v8h a0 = *(const v8h*)&sxr[a1off0 + kb * 16];
                v8h a1 = *(const v8h*)&sxr[a1off1 + kb * 16];
                v8h bc0 = rb0[kb & 3], bc1 = rb1[kb & 3];
                C1[0][0] = MFMA32H(bc0, a0, C1[0][0]);
                C1[0][1] = MFMA32H(bc1, a0, C1[0][1]);
                C1[1][0] = MFMA32H(bc0, a1, C1[1][0]);
                C1[1][1] = MFMA32H(bc1, a1, C1[1][1]);
            }
        }
        // NO barrier: epilogue writes the OTHER buffer (WAR eliminated)

        // ---- epilogue: x_{l+1} = sin(C1) + sin(G) -> sxw; G-hoisted ----
        {
            v8h gb0 = *(const v8h*)(gf + ((l * 8 + w * 2 + 0) * 64 + lane) * 8);
            v8h gb1 = *(const v8h*)(gf + ((l * 8 + w * 2 + 1) * 64 + lane) * 8);
            #pragma unroll
            for (int m = 0; m < 2; m++) {
                v8h ga = *(const v8h*)&s_g[(m * 32 + m32) * GSTRIDE + l * 8];
                v16f Z = {};
                v16f G0 = MFMA32H(gb0, ga, Z);
                v16f G1 = MFMA32H(gb1, ga, Z);
                const int rowb = (m * 32 + m32) * XSTRIDE;
                #pragma unroll
                for (int tt = 0; tt < 2; tt++) {
                    const int cb = rowb + w * 64 + tt * 32 + h * 4;
                    #pragma unroll
                    for (int rq = 0; rq < 4; rq++) {
                        v4h pv;
                        #pragma unroll
                        for (int j = 0; j < 4; j++) {
                            float gv = tt ? G1[rq * 4 + j] : G0[rq * 4 + j];
                            pv[j] = (_Float16)(sin_hw(C1[m][tt][rq * 4 + j])
                                             + sin_hw(gv));
                        }
                        *(v4h*)(sxw + cb + rq * 8) = pv;    // 8B aligned
                    }
                }
            }
        }
        __syncthreads();   // RAW: x_{l+1} fully written before head reads it

        // ---- head GEMM, 32x32x16: wave = quadrant (mq,tq); reads sxw;
        //      whh 32-col tiles = B; ring-4/dist-3 ----
        {
            const float b2 = bhhs[l * 64 + tq * 32 + m32];
            v16f C2;
            #pragma unroll
            for (int r = 0; r < 16; r++) C2[r] = b2;
            const short* bp2 = whh + l * 16384 + tq * 512 + lane * 8;
            v8h bc[4];
            #pragma unroll
            for (int p = 0; p < 3; p++)
                bc[p] = *(const v8h*)(bp2 + p * 1024);
            const int aoff = mq ? a1off1 : a1off0;
            #pragma unroll
            for (int kb = 0; kb < 16; kb++) {
                if (kb + 3 < 16)
                    bc[(kb + 3) & 3] = *(const v8h*)(bp2 + (kb + 3) * 1024);
                v8h a = *(const v8h*)&sxw[aoff + kb * 16];
                C2 = MFMA32H(a, bc[kb & 3], C2);
            }
            #pragma unroll
            for (int r = 0; r < 16; r++) cout[r] += sin_hw(C2[r]);
        }
        // no barrier: GEMM1(l+1) reads the same buffer head just read
    }

    // ---- store x_out: row = mq*32 + regpat, col = tq*32 + m32 (32-wide) ----
    #pragma unroll
    for (int r = 0; r < 16; r++) {
        const int orow = row0 + mq * 32 + (r & 3) + 8 * (r >> 2) + 4 * h;
        out[orow * 64 + tq * 32 + m32] = cout[r];
    }
}

extern "C" void kernel_launch(void* const* d_in, const int* in_sizes, int n_in,
                              void* d_out, int out_size, void* d_ws, size_t ws_size,
                              hipStream_t stream) {
    const float* pos   = (const float*)d_in[0];
    const float* gfeat = (const float*)d_in[1];
    const float* ffnA  = (const float*)d_in[2];
    const float* W0    = (const float*)d_in[3];
    const float* b0    = (const float*)d_in[4];
    const float* Wh    = (const float*)d_in[5];
    const float* bh    = (const float*)d_in[6];
    const float* Whh   = (const float*)d_in[7];
    const float* bhh   = (const float*)d_in[8];
    float* out = (float*)d_out;
    const int N = in_sizes[0] / 3;

    // ws: wh 327680 | whh 81920 | gf 20480 shorts, then bhs 1280 | bhhs 320 f32
    short* wh  = (short*)d_ws;
    short* whh = wh + 327680;
    short* gf  = whh + 81920;
    float* bhs  = (float*)(gf + 20480);     // byte offset 860160, 16B aligned
    float* bhhs = bhs + 1280;

    ffb_pack<<<217, 256, 0, stream>>>(Wh, Whh, ffnA, bh, bhh,
                                      wh, whh, gf, bhs, bhhs);
    ffb_main<<<N / TM, 256, 0, stream>>>(pos, gfeat, W0, b0, bhs, bhhs,
                                         wh, whh, gf, out);
}

// Round 12
// 225.966 us; speedup vs baseline: 1.1233x; 1.0571x over previous
//
#include <hip/hip_runtime.h>

// FFB encoder fused kernel, MI355X (gfx950). Round 22.
//  R21 post-mortem: 1-barrier/layer dbuf at 8 waves = 177us > R18's 154 at
//  12 waves -> wave count beats barrier count; residency ladder closed.
//  Model fix: 32x32x16 MFMA = ~32 SIMD-cycles -> GEMM1 = 2048 cyc/wave;
//  MFMA arithmetic floor = 29% of wall == measured MfmaUtil. All pipes sum
//  ~40%; 60% is NO-ISSUE stall despite 3 decorrelated blocks/SIMD.
//  New suspect: I$ THRASH. The trip-5 l-loop fully unrolls -> ~25-30KB body
//  vs 32KB I$, 12 waves at decorrelated phases -> continual I$ misses stall
//  issue on every pipe. Explains the session: the only win (fract removal)
//  deleted ~6KB of code; every code-adding change was neutral/worse.
//  R22: (1) #pragma unroll 1 on the l-loop (body ~5KB, fits I$; inner kb
//  loops stay unrolled for ring indexing). (2) bias back into C1-init
//  (R12-proven clean at (256,3); -64 v_add/wave-layer, less code).
//  Prediction: I$ theory right -> 132-144us, MfmaUtil ~38; wrong -> flat.
//  Tripwires: WRITE 32.77MB / FETCH 14.5MB / VGPR ~80 / absmax 0.0625.
//  If flat: all axes tested -> declare structural ceiling next round.
//  Kept from R18 (best, 154us): operand-swapped GEMM1/grid, ring-4/dist-3
//  both GEMMs, epilogue G-hoist, raw v_sin (no fract), packed-b64 layer-0 &
//  epilogue stores, 32x32x16 head, K5-prescaled weights/biases, stride-264
//  LDS, 2 barriers/layer, launch_bounds(256,3).

#define TM 64
#define XSTRIDE 264
#define GSTRIDE 48
#define K5 0.79577471545947667f         // 5/(2*pi)

typedef __attribute__((ext_vector_type(8))) _Float16 v8h;
typedef __attribute__((ext_vector_type(4))) _Float16 v4h;
typedef __attribute__((ext_vector_type(4))) float v4f;
typedef __attribute__((ext_vector_type(16))) float v16f;

#define MFMA32H(a, b, c) __builtin_amdgcn_mfma_f32_32x32x16_f16(a, b, c, 0, 0, 0)

// Raw v_sin_f32: input in revolutions; HW range reduction covers |u| << 256.
__device__ __forceinline__ float sin_hw(float u) {
    return __builtin_amdgcn_sinf(u);
}

__device__ __forceinline__ short f16s(float x) {      // RNE f32->f16
    _Float16 hh = (_Float16)x;
    return __builtin_bit_cast(short, hh);
}

// ---------------- weight packing ----------------
// wh   f16: [l][kb16][nt8][lane64][8]  (327680 shorts), scaled by K5
// whh  f16: [l][kb16][nt2][lane64][8]  (81920 shorts),  scaled by K5  (32-col tiles)
// gf   f16: [l][nt8][lane64][8]        (20480 shorts),  ffnA*2^(l-1)
// bhs  f32: [l][256]  = bh*K5          (1280 floats)
// bhhs f32: [l][64]   = bhh*K5         (320 floats)
__global__ __launch_bounds__(256) void ffb_pack(
    const float* __restrict__ Wh, const float* __restrict__ Whh,
    const float* __restrict__ ffnA,
    const float* __restrict__ bh, const float* __restrict__ bhh,
    short* __restrict__ wh, short* __restrict__ whh, short* __restrict__ gf,
    float* __restrict__ bhs, float* __restrict__ bhhs)
{
    int t = blockIdx.x * 256 + threadIdx.x;
    if (t < 40960) {                       // (l, kb, nt, lane)
        int lane = t & 63, nt = (t >> 6) & 7, kb = (t >> 9) & 15, l = t >> 13;
        int n = nt * 32 + (lane & 31);
        int k0 = kb * 16 + (lane >> 5) * 8;
        short hs[8];
        #pragma unroll
        for (int jj = 0; jj < 8; jj++)
            hs[jj] = f16s(Wh[(l * 256 + k0 + jj) * 256 + n] * K5);
        *(v8h*)(wh + t * 8) = *(v8h*)hs;
    } else if (t < 51200) {
        int t2 = t - 40960;                // (l, kb16, nt2, lane)
        int lane = t2 & 63, nt = (t2 >> 6) & 1, kb = (t2 >> 7) & 15, l = t2 >> 11;
        int n = nt * 32 + (lane & 31);
        int k0 = kb * 16 + (lane >> 5) * 8;
        short hs[8];
        #pragma unroll
        for (int jj = 0; jj < 8; jj++)
            hs[jj] = f16s(Whh[(l * 256 + k0 + jj) * 64 + n] * K5);
        *(v8h*)(whh + t2 * 8) = *(v8h*)hs;
    } else if (t < 53760) {
        int t3 = t - 51200;                // (l, nt, lane)
        int lane = t3 & 63, nt = (t3 >> 6) & 7, l = t3 >> 9;
        int n = nt * 32 + (lane & 31);
        const float sc = 0.5f * (float)(1 << l);       // 2^(l-1), exact
        short hs[8];
        #pragma unroll
        for (int jj = 0; jj < 8; jj++)
            hs[jj] = f16s(ffnA[(l * 8 + jj) * 256 + n] * sc);
        *(v8h*)(gf + t3 * 8) = *(v8h*)hs;
    } else if (t < 55040) {
        int t4 = t - 53760;
        bhs[t4] = bh[t4] * K5;
    } else if (t < 55360) {
        int t5 = t - 55040;
        bhhs[t5] = bhh[t5] * K5;
    }
}

// ---------------- main fused kernel ----------------
__global__ __launch_bounds__(256, 3) void ffb_main(
    const float* __restrict__ pos, const float* __restrict__ gfeat,
    const float* __restrict__ W0, const float* __restrict__ b0,
    const float* __restrict__ bhs, const float* __restrict__ bhhs,
    const short* __restrict__ wh, const short* __restrict__ whh,
    const short* __restrict__ gf,
    float* __restrict__ out)
{
    __shared__ __align__(16) short s_x[TM * XSTRIDE];   // f16  (33792 B)
    __shared__ __align__(16) short s_g[TM * GSTRIDE];   // f16  (6144 B)

    const int tid = threadIdx.x;
    const int row0 = blockIdx.x * TM;
    const int lane = tid & 63;
    const int w = tid >> 6;
    const int m32 = lane & 31;
    const int h = lane >> 5;
    const int mq = w >> 1;                 // head-GEMM quadrant row-tile
    const int tq = w & 1;                  // head-GEMM quadrant col-tile

    for (int k2 = tid; k2 < TM * 40; k2 += 256) {
        int r = k2 / 40, f = k2 % 40;
        s_g[r * GSTRIDE + f] = f16s(gfeat[row0 * 40 + k2]);
    }

    // layer 0: x = sin(5*(pos@W0 + b0)); wave w = rows w*16..+15,
    // thread = cols 4*lane..+3; f32 math; packed b64 stores.
    {
        const int c0 = 4 * lane;
        const int r0 = w * 16;
        float w0c[3][4], bq[4];
        #pragma unroll
        for (int j = 0; j < 4; j++) {
            w0c[0][j] = W0[c0 + j];
            w0c[1][j] = W0[256 + c0 + j];
            w0c[2][j] = W0[512 + c0 + j];
            bq[j] = b0[c0 + j];
        }
        #pragma unroll 4
        for (int r = 0; r < 16; r++) {
            const float p0 = pos[(row0 + r0 + r) * 3 + 0];   // wave-uniform
            const float p1 = pos[(row0 + r0 + r) * 3 + 1];
            const float p2 = pos[(row0 + r0 + r) * 3 + 2];
            v4h pv;
            #pragma unroll
            for (int j = 0; j < 4; j++) {
                float d = p0 * w0c[0][j] + p1 * w0c[1][j] + p2 * w0c[2][j] + bq[j];
                pv[j] = (_Float16)sin_hw(d * K5);
            }
            *(v4h*)(s_x + (r0 + r) * XSTRIDE + c0) = pv;
        }
    }
    __syncthreads();

    float cout[16];
    #pragma unroll
    for (int r = 0; r < 16; r++) cout[r] = 0.f;

    const int a1off0 = m32 * XSTRIDE + h * 8;            // x-row tile 0, + kb*16
    const int a1off1 = (32 + m32) * XSTRIDE + h * 8;     // x-row tile 1

    // NOT unrolled: keep the loop body (~5-6KB) inside the 32KB I$.
    #pragma unroll 1
    for (int l = 0; l < 5; l++) {
        // ---- C1 init with bias (K5-prescaled; R12-proven at 256,3) ----
        // wcol(reg r, h) = w*64 + tt*32 + 8*(r>>2) + 4*h + (r&3)
        v16f C1[2][2];
        {
            const float* bl = bhs + l * 256 + w * 64 + h * 4;
            #pragma unroll
            for (int tt = 0; tt < 2; tt++)
                #pragma unroll
                for (int rq = 0; rq < 4; rq++) {
                    v4f b = *(const v4f*)(bl + tt * 32 + rq * 8);
                    #pragma unroll
                    for (int j = 0; j < 4; j++) {
                        C1[0][tt][rq * 4 + j] = b[j];
                        C1[1][tt][rq * 4 + j] = b[j];
                    }
                }
        }

        // ---- GEMM1 (swapped): wh = A, x = B; ring-4/dist-3 ----
        {
            const short* bp = wh + l * 65536 + (2 * w) * 512 + lane * 8;
            v8h rb0[4], rb1[4];
            #pragma unroll
            for (int p = 0; p < 3; p++) {
                rb0[p] = *(const v8h*)(bp + p * 4096);
                rb1[p] = *(const v8h*)(bp + p * 4096 + 512);
            }
            #pragma unroll
            for (int kb = 0; kb < 16; kb++) {
                if (kb + 3 < 16) {
                    rb0[(kb + 3) & 3] = *(const v8h*)(bp + (kb + 3) * 4096);
                    rb1[(kb + 3) & 3] = *(const v8h*)(bp + (kb + 3) * 4096 + 512);
                }
                v8h a0 = *(const v8h*)&s_x[a1off0 + kb * 16];
                v8h a1 = *(const v8h*)&s_x[a1off1 + kb * 16];
                v8h bc0 = rb0[kb & 3], bc1 = rb1[kb & 3];
                C1[0][0] = MFMA32H(bc0, a0, C1[0][0]);
                C1[0][1] = MFMA32H(bc1, a0, C1[0][1]);
                C1[1][0] = MFMA32H(bc0, a1, C1[1][0]);
                C1[1][1] = MFMA32H(bc1, a1, C1[1][1]);
            }
        }
        __syncthreads();   // all waves done reading x_l

        // ---- epilogue: x = sin(C1) + sin(G); per m-tile, BOTH G MFMAs
        //      issued before sin consumption; packed b64 stores ----
        {
            v8h gb0 = *(const v8h*)(gf + ((l * 8 + w * 2 + 0) * 64 + lane) * 8);
            v8h gb1 = *(const v8h*)(gf + ((l * 8 + w * 2 + 1) * 64 + lane) * 8);
            #pragma unroll
            for (int m = 0; m < 2; m++) {
                v8h ga = *(const v8h*)&s_g[(m * 32 + m32) * GSTRIDE + l * 8];
                v16f Z = {};
                v16f G0 = MFMA32H(gb0, ga, Z);
                v16f G1 = MFMA32H(gb1, ga, Z);
                const int rowb = (m * 32 + m32) * XSTRIDE;
                #pragma unroll
                for (int tt = 0; tt < 2; tt++) {
                    const int cb = rowb + w * 64 + tt * 32 + h * 4;
                    #pragma unroll
                    for (int rq = 0; rq < 4; rq++) {
                        v4h pv;
                        #pragma unroll
                        for (int j = 0; j < 4; j++) {
                            float gv = tt ? G1[rq * 4 + j] : G0[rq * 4 + j];
                            pv[j] = (_Float16)(sin_hw(C1[m][tt][rq * 4 + j])
                                             + sin_hw(gv));
                        }
                        *(v4h*)(s_x + cb + rq * 8) = pv;    // 8B aligned
                    }
                }
            }
        }
        __syncthreads();   // new x visible

        // ---- head GEMM, 32x32x16: wave = quadrant (mq,tq); whh 32-col
        //      tiles = B; ring-4/dist-3 ----
        {
            const float b2 = bhhs[l * 64 + tq * 32 + m32];
            v16f C2;
            #pragma unroll
            for (int r = 0; r < 16; r++) C2[r] = b2;
            const short* bp2 = whh + l * 16384 + tq * 512 + lane * 8;
            v8h bc[4];
            #pragma unroll
            for (int p = 0; p < 3; p++)
                bc[p] = *(const v8h*)(bp2 + p * 1024);
            const int aoff = mq ? a1off1 : a1off0;
            #pragma unroll
            for (int kb = 0; kb < 16; kb++) {
                if (kb + 3 < 16)
                    bc[(kb + 3) & 3] = *(const v8h*)(bp2 + (kb + 3) * 1024);
                v8h a = *(const v8h*)&s_x[aoff + kb * 16];
                C2 = MFMA32H(a, bc[kb & 3], C2);
            }
            #pragma unroll
            for (int r = 0; r < 16; r++) cout[r] += sin_hw(C2[r]);
        }
        // no barrier: next GEMM1 reads same x; overwrites after its own barrier
    }

    // ---- store x_out: row = mq*32 + regpat, col = tq*32 + m32 (32-wide) ----
    #pragma unroll
    for (int r = 0; r < 16; r++) {
        const int orow = row0 + mq * 32 + (r & 3) + 8 * (r >> 2) + 4 * h;
        out[orow * 64 + tq * 32 + m32] = cout[r];
    }
}

extern "C" void kernel_launch(void* const* d_in, const int* in_sizes, int n_in,
                              void* d_out, int out_size, void* d_ws, size_t ws_size,
                              hipStream_t stream) {
    const float* pos   = (const float*)d_in[0];
    const float* gfeat = (const float*)d_in[1];
    const float* ffnA  = (const float*)d_in[2];
    const float* W0    = (const float*)d_in[3];
    const float* b0    = (const float*)d_in[4];
    const float* Wh    = (const float*)d_in[5];
    const float* bh    = (const float*)d_in[6];
    const float* Whh   = (const float*)d_in[7];
    const float* bhh   = (const float*)d_in[8];
    float* out = (float*)d_out;
    const int N = in_sizes[0] / 3;

    // ws: wh 327680 | whh 81920 | gf 20480 shorts, then bhs 1280 | bhhs 320 f32
    short* wh  = (short*)d_ws;
    short* whh = wh + 327680;
    short* gf  = whh + 81920;
    float* bhs  = (float*)(gf + 20480);     // byte offset 860160, 16B aligned
    float* bhhs = bhs + 1280;

    ffb_pack<<<217, 256, 0, stream>>>(Wh, Whh, ffnA, bh, bhh,
                                      wh, whh, gf, bhs, bhhs);
    ffb_main<<<N / TM, 256, 0, stream>>>(pos, gfeat, W0, b0, bhs, bhhs,
                                         wh, whh, gf, out);
}